// Round 2
// baseline (3620.252 us; speedup 1.0000x reference)
//
#include <hip/hip_runtime.h>
#include <stdint.h>

// Conductance-LIF network, persistent event-driven kernel. Round 8.
//
// r6 (647us) vs r7 (663us) showed: poll-path + gather-latency micro-opts are
// NULL; only structural sync removals ever moved the number (r3-r5 3.0us/step
// -> r6 2.53). The remaining skeleton was the per-step intra-block convoy:
// 12-wave __syncthreads (max-coupling of straggler jitter) -> LDS partial
// round trip -> 192-thread tail (36 ds_reads + LIF) -> publish-at-the-end.
//
// r8 removes ALL of it: wave-autonomous convoys.
//   * 256 blocks x 384 threads; j = blockIdx&7 (XCD slice affinity: the
//     1.77 MB W/WF column slice stays L2-resident, r6-measured FETCH best),
//     b = blockIdx>>3. Each of the 6 waves owns ONE 32-neuron output word:
//     cols j*192 + wv*32 .. +31.
//   * Gather: lane = (row-quarter wl>>4, col-pair wl&15); one float2 load
//     instr covers 4 rows x 32 cols (4 x 128B contiguous segments). Rows are
//     queued by class (ct0 / ct1 / FF) into 4-deep homogeneous batches so
//     loads pipeline and accumulate without per-row cndmask splits.
//   * Detection: lanes 0..47 poll all 48 words of (b, t-1) with ONE load
//     instruction; ballot(tag==t) finds arrivals; bits + ct-masks are
//     lane-resident and readlane'd per fresh word (eager arrival-order
//     drain). First poll issued before the FF drain so its latency hides.
//   * Per-wave epilogue: 2 x shfl_xor quarter-reduce + 1 shfl redistribute
//     -> 1 col/lane -> LIF -> ballot -> lane 0 publishes its word
//     immediately. NO __syncthreads anywhere in the loop, NO LDS at all.
// Sync protocol unchanged from r6/r7 (proven): flag+data in ONE 64-bit word
// (hi32 = t+1 for step-t spikes, lo32 = 32 spike bits), relaxed agent-scope
// atomics only, time-indexed recpub[32][256][48] (no overwrite races), tags
// 1..256 never collide with the 0xAAAAAAAA ws poison. All 256 blocks (1536
// waves) are co-resident (6 waves/block << capacity) and every wave publishes
// step t before any wave needs it at t+1 (induction) -> deadlock-free.
// Correctness never depends on block->XCD placement (perf heuristic only).

#define ATOMIC_LD(p) __hip_atomic_load((p), __ATOMIC_RELAXED, __HIP_MEMORY_SCOPE_AGENT)

// one batched load: rows R0..R3 (quarter q picks), 32 cols, accumulate float2.
// Slots >= N contribute 0 (their row regs are 0 -> in-bounds dummy load of row 0).
#define GATH4(BASEPTR, R0, R1, R2, R3, N, AX, AY) do {                        \
    const uint32_t _rs = (q == 0) ? (R0) : ((q == 1) ? (R1) : ((q == 2) ? (R2) : (R3))); \
    const float2 _w = *(const float2*)((BASEPTR) + (size_t)_rs * 1536u + colb); \
    float _wx = _w.x, _wy = _w.y;                                             \
    if (q >= (N)) { _wx = 0.f; _wy = 0.f; }                                   \
    (AX) += _wx; (AY) += _wy;                                                 \
} while (0)

// push row RV into a 4-slot queue; flush (issue one batched load) when full.
#define QPUSH(Q0, Q1, Q2, Q3, QN, BASEPTR, AX, AY, RV) do {                   \
    if ((QN) == 0) (Q0) = (RV); else if ((QN) == 1) (Q1) = (RV);              \
    else if ((QN) == 2) (Q2) = (RV); else (Q3) = (RV);                        \
    if (++(QN) == 4) { GATH4(BASEPTR, Q0, Q1, Q2, Q3, 4, AX, AY); (QN) = 0; } \
} while (0)

#define FM_LIST(X) X(0) X(1) X(2) X(3) X(4) X(5) X(6) X(7) X(8) X(9) X(10) X(11)

__global__ __launch_bounds__(384) void snn_lif_kernel(
    const float* __restrict__ I,     // [32][256][768] input spikes (0/1)
    const float* __restrict__ W,     // [1536][1536] recurrent weights (row = pre)
    const float* __restrict__ WF,    // [768][1536]  FF weights (row = input)
    const float* __restrict__ sf,    // [2][2] scaling (pre ct, post ct)
    const float* __restrict__ sfF,   // [1][2] FF scaling (post ct)
    const int*   __restrict__ ct,    // [1536] cell type 0/1
    float* __restrict__ out,         // spk [32][256][1536] then volt [...]
    uint64_t* __restrict__ recpub)   // [32][256][48]: (tag<<32)|spike-bits
{
    const int tid = threadIdx.x;
    const int j   = blockIdx.x & 7;    // column slice -> XCD affinity (perf only)
    const int b   = blockIdx.x >> 3;   // batch
    const int wv  = tid >> 6;          // wave 0..5: owns word j*6+wv
    const int wl  = tid & 63;

    // ---- lane-resident ct masks: lane k (k<48) holds ct bits of word k ----
    uint32_t cmlane = 0;
    for (int r = 0; r < 24; ++r) {
        const int c = ct[r * 64 + wl];
        const uint64_t bal = __ballot(c != 0);
        if (wl == 2 * r)     cmlane = (uint32_t)bal;
        if (wl == 2 * r + 1) cmlane = (uint32_t)(bal >> 32);
    }

    // ---- owner col (lane&31) constants for LIF ----
    const int   mcol = j * 192 + wv * 32 + (wl & 31);
    const int   myct = ct[mcol];
    const float s0m  = sf[myct];        // pre-ct0 rows scale
    const float s1m  = sf[2 + myct];    // pre-ct1 rows scale
    const float sFm  = sfF[myct];
    const float lc   = (myct == 0) ? (1.0f / 200.0f) : (1.0f / 100.0f);
    const float refsteps = (myct == 0) ? 2.0f : 1.0f;
    const float ar0 = expf(-1.0f / 0.5f),  ad0 = expf(-1.0f / 2.0f);
    const float ar1 = expf(-1.0f / 2.0f),  ad1 = expf(-1.0f / 100.0f);
    const float ar2 = expf(-1.0f / 0.5f),  ad2 = expf(-1.0f / 5.0f);
    const float arF = expf(-1.0f / 0.5f),  adF = expf(-1.0f / 2.0f);

    // ---- gather lane geometry: quarter = row within batch, colpair = 2 cols ----
    const int      q    = wl >> 4;                                  // 0..3
    const uint32_t colb = (uint32_t)(j * 192 + wv * 32 + 2 * (wl & 15)); // float idx

    float U = -65.0f, refc = 0.0f;
    float x0 = 0, g0 = 0, x1 = 0, g1 = 0, x2 = 0, g2 = 0, xF = 0, gF = 0;
    const int btbase = b * 256;

    // ---- FF masks for t=0: 12 x ballot of this wave's own I[b,0,:] loads ----
#define DECLFM(i) uint64_t fm##i;
    FM_LIST(DECLFM)
    {
        const uint32_t ib = (uint32_t)btbase * 768u;
#define LD0(i) const float iv##i = I[ib + 64u * i + (uint32_t)wl];
        FM_LIST(LD0)
#define BL0(i) fm##i = __ballot(iv##i > 0.5f);
        FM_LIST(BL0)
    }

    for (int t = 0; t < 256; ++t) {
        float a0x = 0.f, a0y = 0.f, a1x = 0.f, a1y = 0.f, aFx = 0.f, aFy = 0.f;

        // issue the FIRST poll sample early (latency hides under the FF drain)
        const uint32_t pbase = (uint32_t)(btbase + t - 1) * 48u;
        const int      pl    = (wl < 48) ? wl : 47;
        uint64_t pv0 = 0;
        if (t > 0) pv0 = ATOMIC_LD(&recpub[pbase + (uint32_t)pl]);

        // issue next-step input loads (L2-shared across the batch's 48 waves)
        const bool     pre = (t < 255);
        const uint32_t ibn = (uint32_t)(btbase + t + 1) * 768u;
#define LDN(i) float nv##i = 0.f; if (pre) nv##i = I[ibn + 64u * i + (uint32_t)wl];
        FM_LIST(LDN)

        // ---- FF drain (always-ready work; overlaps producers publishing) ----
        {
            uint32_t qf0 = 0, qf1 = 0, qf2 = 0, qf3 = 0; int qfn = 0;
#define FFD(i) { uint64_t mm = fm##i;                                          \
                 while (mm) { const int bi = (int)__builtin_ctzll(mm); mm &= mm - 1; \
                              QPUSH(qf0, qf1, qf2, qf3, qfn, WF, aFx, aFy,     \
                                    (uint32_t)(64 * i + bi)); } }
            FM_LIST(FFD)
            if (qfn) GATH4(WF, qf0, qf1, qf2, qf3, qfn, aFx, aFy);
        }

        // ---- rec: poll all 48 words with one load instr; eager drain ----
        if (t > 0) {
            uint32_t qa0 = 0, qa1 = 0, qa2 = 0, qa3 = 0; int qan = 0;  // ct0 rows
            uint32_t qb0 = 0, qb1 = 0, qb2 = 0, qb3 = 0; int qbn = 0;  // ct1 rows
            uint64_t seen = 0;
            const uint64_t FULL = 0x0000FFFFFFFFFFFFull;
            uint32_t pbits = (uint32_t)pv0;
            uint32_t ptag  = (uint32_t)(pv0 >> 32);
            for (;;) {
                const uint64_t rdy   = __ballot(ptag == (uint32_t)t);
                uint64_t       fresh = rdy & ~seen & FULL;
                seen |= fresh;
                while (fresh) {
                    const int k = (int)__builtin_ctzll(fresh); fresh &= fresh - 1;
                    const uint32_t bits = (uint32_t)__builtin_amdgcn_readlane(pbits, k);
                    const uint32_t cmk  = (uint32_t)__builtin_amdgcn_readlane(cmlane, k);
                    uint32_t bA = bits & ~cmk;        // pre-ct0 rows
                    uint32_t bB = bits & cmk;         // pre-ct1 rows
                    const uint32_t rb = (uint32_t)k * 32u;
                    while (bA) { const int bi = (int)__builtin_ctz(bA); bA &= bA - 1;
                                 QPUSH(qa0, qa1, qa2, qa3, qan, W, a0x, a0y, rb + (uint32_t)bi); }
                    while (bB) { const int bi = (int)__builtin_ctz(bB); bB &= bB - 1;
                                 QPUSH(qb0, qb1, qb2, qb3, qbn, W, a1x, a1y, rb + (uint32_t)bi); }
                }
                if (seen == FULL) break;
                const uint64_t pv = ATOMIC_LD(&recpub[pbase + (uint32_t)pl]);
                pbits = (uint32_t)pv;
                ptag  = (uint32_t)(pv >> 32);
            }
            if (qan) GATH4(W, qa0, qa1, qa2, qa3, qan, a0x, a0y);
            if (qbn) GATH4(W, qb0, qb1, qb2, qb3, qbn, a1x, a1y);
        }

        // ---- FF masks for t+1 (loads long since complete) ----
#define BLN(i) fm##i = __ballot(nv##i > 0.5f);
        FM_LIST(BLN)

        // ---- quarter-reduce (xor 16,32): every lane gets colpair (wl&15) sum ----
        a0x += __shfl_xor(a0x, 16); a0x += __shfl_xor(a0x, 32);
        a0y += __shfl_xor(a0y, 16); a0y += __shfl_xor(a0y, 32);
        a1x += __shfl_xor(a1x, 16); a1x += __shfl_xor(a1x, 32);
        a1y += __shfl_xor(a1y, 16); a1y += __shfl_xor(a1y, 32);
        aFx += __shfl_xor(aFx, 16); aFx += __shfl_xor(aFx, 32);
        aFy += __shfl_xor(aFy, 16); aFy += __shfl_xor(aFy, 32);

        // ---- redistribute: lane owns col (wl&31) = comp (wl&1) of pair (wl>>1) ----
        const int srcl = wl >> 1;
        float z0, z1, zF;
        {
            const float e0 = __shfl(a0x, srcl), o0 = __shfl(a0y, srcl);
            const float e1 = __shfl(a1x, srcl), o1 = __shfl(a1y, srcl);
            const float eF = __shfl(aFx, srcl), oF = __shfl(aFy, srcl);
            z0 = (wl & 1) ? o0 : e0;
            z1 = (wl & 1) ? o1 : e1;
            zF = (wl & 1) ? oF : eF;
        }
        z0 *= s0m; z1 *= s1m; zF *= sFm;

        // ---- synapse + LIF (identical arithmetic to r6/r7, verified) ----
        x0 = ar0 * x0 + z0;  g0 = ad0 * g0 + x0;   // syn0 (pre ct0)
        x1 = ar1 * x1 + z0;  g1 = ad1 * g1 + x1;   // syn1 (pre ct0, same z0)
        x2 = ar2 * x2 + z1;  g2 = ad2 * g2 + x2;   // syn2 (pre ct1)
        xF = arF * xF + zF;  gF = adF * gF + xF;   // feed-forward
        const float gtot = g0 + 0.5f * g1 + g2 + gF;   // gbar=[1,.5,1], FF 1
        const float gE   = -70.0f * g2;                // gbar*Erev=[0,0,-70], FF 0
        const float Isyn = gE - gtot * U;
        float Un = U + lc * (10.0f * (-65.0f - U) + Isyn);
        if (refc > 0.0f) Un = -65.0f;
        refc = fmaxf(refc - 1.0f, 0.0f);
        const bool s = (Un - (-50.0f)) >= 0.0f;

        // ---- publish IMMEDIATELY (lanes 32..63 replicate lanes 0..31) ----
        const uint64_t bal = __ballot(s);
        if (wl == 0) {
            const uint32_t widx = (uint32_t)(btbase + t) * 48u + (uint32_t)(j * 6 + wv);
            const uint64_t v = ((uint64_t)(uint32_t)(t + 1) << 32) | (uint32_t)bal;
            __hip_atomic_store(&recpub[widx], v, __ATOMIC_RELAXED,
                               __HIP_MEMORY_SCOPE_AGENT);
        }
        const float Uo = s ? -65.0f : Un;
        refc = s ? refsteps : refc;
        U = Uo;
        if (wl < 32) {
            const uint32_t oidx = (uint32_t)(btbase + t) * 1536u + (uint32_t)mcol;
            __builtin_nontemporal_store(s ? 1.0f : 0.0f, &out[oidx]);
            __builtin_nontemporal_store(Uo, &out[12582912u + oidx]);
        }
    }
}

extern "C" void kernel_launch(void* const* d_in, const int* in_sizes, int n_in,
                              void* d_out, int out_size, void* d_ws, size_t ws_size,
                              hipStream_t stream) {
    const float* I   = (const float*)d_in[0];   // input_spikes (32,256,768)
    const float* W   = (const float*)d_in[1];   // weights (1536,1536)
    const float* WF  = (const float*)d_in[2];   // weights_FF (768,1536)
    const float* sf  = (const float*)d_in[3];   // scaling_factors (2,2)
    const float* sfF = (const float*)d_in[4];   // scaling_factors_FF (1,2)
    const int*   ct  = (const int*)d_in[5];     // cell_type_indices (1536)
    // d_in[6] cell_type_indices_FF: all zeros, folded into sfF indexing.

    uint64_t* recpub = (uint64_t*)d_ws;   // 32*256*48*8 = 3,145,728 B

    snn_lif_kernel<<<dim3(256), dim3(384), 0, stream>>>(
        I, W, WF, sf, sfF, ct, (float*)d_out, recpub);
}

// Round 3
// 935.791 us; speedup vs baseline: 3.8687x; 3.8687x over previous
//
#include <hip/hip_runtime.h>
#include <stdint.h>

// Conductance-LIF network, persistent event-driven kernel. Round 9.
//
// Evidence: r6=647us (best). r7 (poll-RTT/gather-latency micro-opts)=NULL ->
// sync RTT not dominant. r8 (wave-autonomous, serialized drain)=3559us ->
// row-parallelism across waves + barrier/tail is the RIGHT structure.
// Remaining theory: straggler MAX-coupling. Each batch's blocks are all-to-all
// coupled per step; period = E[max over producers] of (gather jitter + barrier
// + serial tail). r9 shrinks the max-pool and the producer tail:
//   * 4 slices (not 8): 128 blocks x 768 threads, 384 cols each. Half the
//     independent stragglers per consumed set. W+WF slice = 3.54 MB, still
//     fits 4 MB per-XCD L2 (blockIdx%8 puts slice j on XCDs {j, j+4} under
//     the round-robin heuristic -- perf only, never correctness).
//   * Row-partitioned gather IDENTICAL to r6: 12 waves x 4 words x ~10 rows,
//     2 independent loads/row (float4 cols 0-255 + float2 cols 256-383,
//     64/64 lanes used vs r6's 48/64).
//   * PARALLEL tail: 384 cols / 12 waves = exactly one 32-neuron word per
//     wave. Each wave reduces its own 32 cols (18 conflict-free LDS scalar
//     reads + 1 shfl_xor(32)), LIFs, publishes its word immediately. The
//     producer-side serial tail shrinks ~400 -> ~150 cyc and publishes in
//     parallel across 12 waves.
// Sync protocol unchanged from r6 (proven): flag+data in ONE 64-bit word
// (hi32 = t+1 for step-t spikes, lo32 = 32 spike bits), relaxed agent-scope
// atomics, time-indexed recpub[32][256][48], tags 1..256 never collide with
// the 0xAAAAAAAA ws poison. All 128 blocks co-resident (<< 256 CUs); publish
// for step t precedes any wait on step-t words (induction) -> deadlock-free.
// Partials double-buffered -> single barrier per step, no second barrier.

#define ATOMIC_LD(p) __hip_atomic_load((p), __ATOMIC_RELAXED, __HIP_MEMORY_SCOPE_AGENT)

__global__ __launch_bounds__(768) void snn_lif_kernel(
    const float* __restrict__ I,     // [32][256][768] input spikes (0/1)
    const float* __restrict__ W,     // [1536][1536] recurrent weights (row = pre)
    const float* __restrict__ WF,    // [768][1536]  FF weights (row = input)
    const float* __restrict__ sf,    // [2][2] scaling (pre ct, post ct)
    const float* __restrict__ sfF,   // [1][2] FF scaling (post ct)
    const int*   __restrict__ ct,    // [1536] cell type 0/1
    float* __restrict__ out,         // spk [32][256][1536] then volt [...]
    uint64_t* __restrict__ recpub)   // [32][256][48]: (tag<<32)|spike-bits
{
    const int tid = threadIdx.x;
    const int j   = blockIdx.x & 3;    // 384-col slice; XCD {j,j+4} (perf only)
    const int b   = blockIdx.x >> 2;   // batch
    const int wv  = tid >> 6;          // wave 0..11
    const int wl  = tid & 63;          // lane

    __shared__ float    partf[2][12][3][384];  // dbuf x wave x {ct0,ct1,FF} x col
    __shared__ uint32_t ctm32_sh[48];          // cell-type bits per 32-neuron word

    // ---- cell-type bitmask via block-wide ballots (2 x 768) ----
    for (int r = 0; r < 2; ++r) {
        int c = ct[r * 768 + tid];
        uint64_t bal = __ballot(c != 0);
        if (wl == 0) {
            ctm32_sh[r * 24 + wv * 2]     = (uint32_t)bal;
            ctm32_sh[r * 24 + wv * 2 + 1] = (uint32_t)(bal >> 32);
        }
    }
    __syncthreads();

    // this wave's 4 gather-word ct masks (rows wv*128 .. wv*128+127)
    uint32_t cmw[4];
    #pragma unroll
    for (int k = 0; k < 4; ++k) cmw[k] = ctm32_sh[wv * 4 + k];

    // ---- owner col (one 32-col word per wave; lanes 32-63 mirror 0-31) ----
    const int   m    = j * 384 + wv * 32 + (wl & 31);
    const int   myct = ct[m];
    const float s0m  = sf[myct];
    const float s1m  = sf[2 + myct];
    const float sFm  = sfF[myct];
    const float lcoef = (myct == 0) ? (1.0f / 200.0f) : (1.0f / 100.0f);
    const float refsteps = (myct == 0) ? 2.0f : 1.0f;
    const float ar0 = expf(-1.0f / 0.5f),  ad0 = expf(-1.0f / 2.0f);
    const float ar1 = expf(-1.0f / 2.0f),  ad1 = expf(-1.0f / 100.0f);
    const float ar2 = expf(-1.0f / 0.5f),  ad2 = expf(-1.0f / 5.0f);
    const float arF = expf(-1.0f / 0.5f),  adF = expf(-1.0f / 2.0f);

    float U = -65.0f, refc = 0.0f;
    float x0 = 0, g0 = 0, x1 = 0, g1 = 0, x2 = 0, g2 = 0, xF = 0, gF = 0;

    const int btbase = b * 256;
    // gather column addresses (float index): float4 covers cols 0-255 of the
    // slice, float2 covers 256-383 -- all 64 lanes used, both loads independent
    const uint32_t c4 = (uint32_t)(j * 384) + (uint32_t)(wl * 4);
    const uint32_t c2 = (uint32_t)(j * 384) + 256u + (uint32_t)(wl * 2);

    // initial FF mask: wave wv ballots inputs wv*64..+63 of I[b,0,:]
    uint64_t fmask;
    {
        float iv = __builtin_nontemporal_load(
            &I[(uint32_t)btbase * 768u + (uint32_t)tid]);
        fmask = __ballot(iv > 0.5f);
    }

    for (int t = 0; t < 256; ++t) {
        // issue the first poll sample early (latency hides under FF drain)
        const uint32_t pbase = (uint32_t)(btbase + t - 1) * 48u + (uint32_t)(wv * 4);
        uint64_t pv = 0;
        if (t > 0 && wl < 4)
            pv = ATOMIC_LD(&recpub[pbase + (uint32_t)wl]);

        // prefetch next-step input (consumed by the ballot before the barrier)
        float ivn = 0.0f;
        if (t < 255)
            ivn = __builtin_nontemporal_load(
                &I[(uint32_t)(btbase + t + 1) * 768u + (uint32_t)tid]);

        float4 a04 = make_float4(0.f, 0.f, 0.f, 0.f), a14 = a04, aF4 = a04;
        float2 a02 = make_float2(0.f, 0.f),           a12 = a02, aF2 = a02;

        // ---- FF rows (always ready; fmask is this wave's own ballot) ----
        {
            uint64_t mm = fmask;   // wave-uniform
            while (mm) {
                const int bit = __builtin_ctzll(mm);
                mm &= mm - 1;
                const float* rp = WF + (size_t)(wv * 64 + bit) * 1536u;
                const float4 w4 = *(const float4*)(rp + c4);
                const float2 w2 = *(const float2*)(rp + c2);
                aF4.x += w4.x; aF4.y += w4.y; aF4.z += w4.z; aF4.w += w4.w;
                aF2.x += w2.x; aF2.y += w2.y;
            }
        }

        // ---- poll 4 rec words; gather each on arrival (r6-proven loop) ----
        if (t > 0) {
            uint32_t ready = 0;
            for (;;) {
                const uint32_t plo = (uint32_t)pv;
                const uint32_t phi = (uint32_t)(pv >> 32);
                #pragma unroll
                for (int k = 0; k < 4; ++k) {
                    if (ready & (1u << k)) continue;
                    if ((uint32_t)__builtin_amdgcn_readlane(phi, k) != (uint32_t)t)
                        continue;                      // not published yet
                    ready |= 1u << k;
                    uint32_t bits = (uint32_t)__builtin_amdgcn_readlane(plo, k);
                    const uint32_t cm   = cmw[k];
                    const uint32_t word = (uint32_t)(wv * 4 + k);
                    while (bits) {                     // wave-uniform row loop
                        const int bit = __builtin_ctz(bits);
                        bits &= bits - 1;
                        const float* rp = W + (size_t)(word * 32u + (uint32_t)bit) * 1536u;
                        const float4 w4 = *(const float4*)(rp + c4);
                        const float2 w2 = *(const float2*)(rp + c2);
                        if ((cm >> bit) & 1u) {
                            a14.x += w4.x; a14.y += w4.y; a14.z += w4.z; a14.w += w4.w;
                            a12.x += w2.x; a12.y += w2.y;
                        } else {
                            a04.x += w4.x; a04.y += w4.y; a04.z += w4.z; a04.w += w4.w;
                            a02.x += w2.x; a02.y += w2.y;
                        }
                    }
                }
                if (ready == 0xFu) break;
                pv = 0;
                if (wl < 4)
                    pv = ATOMIC_LD(&recpub[pbase + (uint32_t)wl]);
            }
        }

        // ---- write partials (all 64 lanes have valid slots) ----
        const int buf = t & 1;
        {
            float* b0 = &partf[buf][wv][0][0];
            float* b1 = &partf[buf][wv][1][0];
            float* b2 = &partf[buf][wv][2][0];
            ((float4*)b0)[wl] = a04;  *(float2*)(b0 + 256 + wl * 2) = a02;
            ((float4*)b1)[wl] = a14;  *(float2*)(b1 + 256 + wl * 2) = a12;
            ((float4*)b2)[wl] = aF4;  *(float2*)(b2 + 256 + wl * 2) = aF2;
        }
        fmask = __ballot(ivn > 0.5f);   // FF mask for step t+1
        __syncthreads();                // partials of ALL waves visible

        // ---- PARALLEL tail: each wave reduces + LIFs its own 32 cols ----
        {
            const int h6 = (wl >> 5) * 6;           // half 0 sums waves 0-5, half 1 waves 6-11
            const int lc = wv * 32 + (wl & 31);     // local col in 0..383
            const float* pf = &partf[buf][0][0][0];
            float z0 = 0.f, z1 = 0.f, zF = 0.f;
            #pragma unroll
            for (int i = 0; i < 6; ++i) {
                const int w = h6 + i;
                z0 += pf[(w * 3 + 0) * 384 + lc];
                z1 += pf[(w * 3 + 1) * 384 + lc];
                zF += pf[(w * 3 + 2) * 384 + lc];
            }
            z0 += __shfl_xor(z0, 32);
            z1 += __shfl_xor(z1, 32);
            zF += __shfl_xor(zF, 32);
            z0 *= s0m; z1 *= s1m; zF *= sFm;

            // synapse + LIF (identical arithmetic to r6, verified)
            x0 = ar0 * x0 + z0;  g0 = ad0 * g0 + x0;   // syn0 (pre ct0)
            x1 = ar1 * x1 + z0;  g1 = ad1 * g1 + x1;   // syn1 (pre ct0, same z0)
            x2 = ar2 * x2 + z1;  g2 = ad2 * g2 + x2;   // syn2 (pre ct1)
            xF = arF * xF + zF;  gF = adF * gF + xF;   // feed-forward
            const float gtot = g0 + 0.5f * g1 + g2 + gF;   // gbar=[1,.5,1], FF 1
            const float gE   = -70.0f * g2;                // gbar*Erev=[0,0,-70], FF 0
            const float Isyn = gE - gtot * U;
            float Un = U + lcoef * (10.0f * (-65.0f - U) + Isyn);
            if (refc > 0.0f) Un = -65.0f;
            refc = fmaxf(refc - 1.0f, 0.0f);
            const bool s = (Un - (-50.0f)) >= 0.0f;

            // publish IMMEDIATELY (lanes 32-63 mirror 0-31; take low 32 bits)
            const uint64_t bal = __ballot(s);
            if (wl == 0) {
                const uint32_t widx = (uint32_t)(btbase + t) * 48u
                                      + (uint32_t)(j * 12 + wv);
                const uint64_t v = ((uint64_t)(uint32_t)(t + 1) << 32) | (uint32_t)bal;
                __hip_atomic_store(&recpub[widx], v, __ATOMIC_RELAXED,
                                   __HIP_MEMORY_SCOPE_AGENT);
            }
            const float Uo = s ? -65.0f : Un;
            refc = s ? refsteps : refc;
            U = Uo;
            const uint32_t oidx = (uint32_t)(btbase + t) * 1536u + (uint32_t)m;
            if (wl < 32)
                __builtin_nontemporal_store(s ? 1.0f : 0.0f, &out[oidx]);
            else
                __builtin_nontemporal_store(Uo, &out[12582912u + oidx]);
        }
        // no second barrier: partials double-buffered; a wave can't reach step
        // t+2's writes before all waves passed step t+1's barrier.
    }
}

extern "C" void kernel_launch(void* const* d_in, const int* in_sizes, int n_in,
                              void* d_out, int out_size, void* d_ws, size_t ws_size,
                              hipStream_t stream) {
    const float* I   = (const float*)d_in[0];   // input_spikes (32,256,768)
    const float* W   = (const float*)d_in[1];   // weights (1536,1536)
    const float* WF  = (const float*)d_in[2];   // weights_FF (768,1536)
    const float* sf  = (const float*)d_in[3];   // scaling_factors (2,2)
    const float* sfF = (const float*)d_in[4];   // scaling_factors_FF (1,2)
    const int*   ct  = (const int*)d_in[5];     // cell_type_indices (1536)
    // d_in[6] cell_type_indices_FF: all zeros, folded into sfF indexing.

    uint64_t* recpub = (uint64_t*)d_ws;   // 32*256*48*8 = 3,145,728 B

    snn_lif_kernel<<<dim3(128), dim3(768), 0, stream>>>(
        I, W, WF, sf, sfF, ct, (float*)d_out, recpub);
}

// Round 4
// 847.404 us; speedup vs baseline: 4.2722x; 1.1043x over previous
//
#include <hip/hip_runtime.h>
#include <stdint.h>

// Conductance-LIF network, persistent event-driven kernel. Round 10.
//
// Evidence ledger: r6=647us (best). r7 (4-deep gather batching + LOST slice
// affinity)=663 NULL — confounded. r8 (wave-autonomous)=3559 — row-parallelism
// mandatory. r9 (double gather width/wave)=834: +1750cyc/step for +9.6 serial
// loads/wave = ~180cyc per serially-exposed row load => the gather loop's
// serial L2 round trips (~13/step) are the dominant attackable term
// (~2300 of 6070 cyc/step).
//
// r10 = r6 VERBATIM (8 slices x 192 cols, j=blockIdx&7 XCD slice affinity so
// the 1.77MB W/WF column slice stays L2-resident, 12 waves x 4 words, 48-lane
// float4 row gather, partials dbuf LDS, ONE barrier, r6 tail+publish) with
// ONLY the gather restructured:
//   * rows pushed into per-class register queues (ct0/ct1/FF), flushed as 4
//     INDEPENDENT float4 loads per lane -> one vmcnt wait per 4 rows instead
//     of per row. ~13 exposed round trips/step -> ~5.
//   * lanes 48-63 run the loads unguarded at lane-47's address (same cache
//     lines, no extra traffic, no exec-mask churn); LDS partial writes stay
//     guarded; their accumulators are never read.
//   * first poll sample issued BEFORE the FF drain (latency hides under it).
// Sync protocol unchanged from r6 (proven): flag+data in ONE 64-bit word
// (hi32 = t+1 for step-t spikes, lo32 = 32 spike bits), relaxed agent-scope
// atomics only, time-indexed recpub[32][256][48], tags 1..256 never collide
// with 0xAAAAAAAA ws poison. 256 blocks co-resident (1 block/CU); publish for
// step t precedes any wait on step-t words (induction) -> deadlock-free.
// Correctness never depends on block->XCD placement (perf heuristic only).

#define ATOMIC_LD(p) __hip_atomic_load((p), __ATOMIC_RELAXED, __HIP_MEMORY_SCOPE_AGENT)

// flush a queue of n (wave-uniform, 1..4) rows: issue n independent float4
// loads, ONE wait, accumulate. Branches are wave-uniform (s_cbranch).
__device__ __forceinline__ void flush4(const float* __restrict__ base,
                                       uint32_t colbase,
                                       uint32_t r0, uint32_t r1,
                                       uint32_t r2, uint32_t r3,
                                       int n, float4& acc) {
    float4 w0, w1, w2, w3;
    w0 = *(const float4*)(base + (size_t)r0 * 1536u + colbase);
    if (n > 1) w1 = *(const float4*)(base + (size_t)r1 * 1536u + colbase);
    if (n > 2) w2 = *(const float4*)(base + (size_t)r2 * 1536u + colbase);
    if (n > 3) w3 = *(const float4*)(base + (size_t)r3 * 1536u + colbase);
    acc.x += w0.x; acc.y += w0.y; acc.z += w0.z; acc.w += w0.w;
    if (n > 1) { acc.x += w1.x; acc.y += w1.y; acc.z += w1.z; acc.w += w1.w; }
    if (n > 2) { acc.x += w2.x; acc.y += w2.y; acc.z += w2.z; acc.w += w2.w; }
    if (n > 3) { acc.x += w3.x; acc.y += w3.y; acc.z += w3.z; acc.w += w3.w; }
}

// push row RV; when the queue holds 4, flush and reset (static reg indexing)
#define QPUSH(Q0, Q1, Q2, Q3, QN, BASE, ACC, RV) do {                         \
    if ((QN) == 0) (Q0) = (RV); else if ((QN) == 1) (Q1) = (RV);              \
    else if ((QN) == 2) (Q2) = (RV); else (Q3) = (RV);                        \
    if (++(QN) == 4) { flush4((BASE), colbase, Q0, Q1, Q2, Q3, 4, (ACC));     \
                       (QN) = 0; }                                            \
} while (0)

__global__ __launch_bounds__(768) void snn_lif_kernel(
    const float* __restrict__ I,     // [32][256][768] input spikes (0/1)
    const float* __restrict__ W,     // [1536][1536] recurrent weights (row = pre)
    const float* __restrict__ WF,    // [768][1536]  FF weights (row = input)
    const float* __restrict__ sf,    // [2][2] scaling (pre ct, post ct)
    const float* __restrict__ sfF,   // [1][2] FF scaling (post ct)
    const int*   __restrict__ ct,    // [1536] cell type 0/1
    float* __restrict__ out,         // spk [32][256][1536] then volt [...]
    uint64_t* __restrict__ recpub)   // [32][256][48]: (tag<<32)|spike-bits
{
    const int tid = threadIdx.x;
    const int j   = blockIdx.x & 7;    // column slice -> XCD under %8 RR (perf)
    const int b   = blockIdx.x >> 3;   // batch
    const int wv  = tid >> 6;          // wave 0..11
    const int wl  = tid & 63;          // lane

    __shared__ float4   part0[2][12][48];   // rec ct0 partials (dbuf)
    __shared__ float4   part1[2][12][48];   // rec ct1 partials
    __shared__ float4   partF[2][12][48];   // FF partials
    __shared__ uint32_t ctm32_sh[48];       // cell-type bits per 32-neuron word

    // ---- cell-type bitmask via block-wide ballots (2 x 768) ----
    for (int r = 0; r < 2; ++r) {
        int c = ct[r * 768 + tid];
        uint64_t bal = __ballot(c != 0);
        if (wl == 0) {
            ctm32_sh[r * 24 + wv * 2]     = (uint32_t)bal;
            ctm32_sh[r * 24 + wv * 2 + 1] = (uint32_t)(bal >> 32);
        }
    }
    __syncthreads();

    // hoist this wave's 4 word ct-masks to registers
    uint32_t cmw[4];
    #pragma unroll
    for (int k = 0; k < 4; ++k) cmw[k] = ctm32_sh[wv * 4 + k];

    // ---- owner-neuron constants (threads 0..191 own neuron m) ----
    const int m = j * 192 + ((tid < 192) ? tid : 0);
    const int   myct = ct[m];
    const float s0m  = sf[myct];
    const float s1m  = sf[2 + myct];
    const float sFm  = sfF[myct];
    const float lc   = (myct == 0) ? (1.0f / 200.0f) : (1.0f / 100.0f);
    const float refsteps = (myct == 0) ? 2.0f : 1.0f;
    const float ar0 = expf(-1.0f / 0.5f),  ad0 = expf(-1.0f / 2.0f);
    const float ar1 = expf(-1.0f / 2.0f),  ad1 = expf(-1.0f / 100.0f);
    const float ar2 = expf(-1.0f / 0.5f),  ad2 = expf(-1.0f / 5.0f);
    const float arF = expf(-1.0f / 0.5f),  adF = expf(-1.0f / 2.0f);

    float U = -65.0f, refc = 0.0f;
    float x0 = 0, g0 = 0, x1 = 0, g1 = 0, x2 = 0, g2 = 0, xF = 0, gF = 0;

    const int  btbase = b * 256;
    const bool gl     = (wl < 48);                          // partial-write lane
    // clamp: lanes 48..63 duplicate lane 47's 16B segment -> loads unguarded,
    // zero extra cache lines; LDS partial writes stay gl-guarded.
    const uint32_t colbase = (uint32_t)(j * 192) + (uint32_t)((wl < 48 ? wl : 47) * 4);

    // initial FF mask: wave wv ballots inputs wv*64..+63 of I[b,0,:]
    uint64_t fmask;
    {
        float iv = __builtin_nontemporal_load(
            &I[(uint32_t)btbase * 768u + (uint32_t)tid]);
        fmask = __ballot(iv > 0.5f);
    }

    for (int t = 0; t < 256; ++t) {
        // issue the first poll sample EARLY (latency hides under the FF drain)
        const uint32_t pbase = (uint32_t)(btbase + t - 1) * 48u + (uint32_t)(wv * 4);
        uint64_t pv = 0;
        if (t > 0 && wl < 4)
            pv = ATOMIC_LD(&recpub[pbase + (uint32_t)wl]);

        // prefetch next-step input (consumed by the ballot before the barrier)
        float ivn = 0.0f;
        if (t < 255)
            ivn = __builtin_nontemporal_load(
                &I[(uint32_t)(btbase + t + 1) * 768u + (uint32_t)tid]);

        float4 a0 = make_float4(0.f, 0.f, 0.f, 0.f);
        float4 a1 = a0, aF = a0;

        // ---- FF rows: 4-deep batched (usually a single flush) ----
        {
            uint32_t qf0 = 0, qf1 = 0, qf2 = 0, qf3 = 0; int qfn = 0;
            uint64_t mm = fmask;   // wave-uniform
            while (mm) {
                const int bit = __builtin_ctzll(mm);
                mm &= mm - 1;
                QPUSH(qf0, qf1, qf2, qf3, qfn, WF, aF, (uint32_t)(wv * 64 + bit));
            }
            if (qfn) flush4(WF, colbase, qf0, qf1, qf2, qf3, qfn, aF);
        }

        // ---- poll 4 rec words; push rows on arrival, flush 4-deep ----
        if (t > 0) {
            uint32_t qa0 = 0, qa1 = 0, qa2 = 0, qa3 = 0; int qan = 0;  // pre-ct0
            uint32_t qb0 = 0, qb1 = 0, qb2 = 0, qb3 = 0; int qbn = 0;  // pre-ct1
            uint32_t ready = 0;
            for (;;) {
                const uint32_t plo = (uint32_t)pv;
                const uint32_t phi = (uint32_t)(pv >> 32);
                #pragma unroll
                for (int k = 0; k < 4; ++k) {
                    if (ready & (1u << k)) continue;
                    if ((uint32_t)__builtin_amdgcn_readlane(phi, k) != (uint32_t)t)
                        continue;                      // not published yet
                    ready |= 1u << k;
                    const uint32_t bits = (uint32_t)__builtin_amdgcn_readlane(plo, k);
                    const uint32_t rb   = (uint32_t)(wv * 4 + k) * 32u;
                    uint32_t bA = bits & ~cmw[k];      // pre-ct0 rows
                    uint32_t bB = bits &  cmw[k];      // pre-ct1 rows
                    while (bA) {
                        const int bit = __builtin_ctz(bA); bA &= bA - 1;
                        QPUSH(qa0, qa1, qa2, qa3, qan, W, a0, rb + (uint32_t)bit);
                    }
                    while (bB) {
                        const int bit = __builtin_ctz(bB); bB &= bB - 1;
                        QPUSH(qb0, qb1, qb2, qb3, qbn, W, a1, rb + (uint32_t)bit);
                    }
                }
                if (ready == 0xFu) break;
                pv = 0;
                if (wl < 4)
                    pv = ATOMIC_LD(&recpub[pbase + (uint32_t)wl]);
            }
            if (qan) flush4(W, colbase, qa0, qa1, qa2, qa3, qan, a0);
            if (qbn) flush4(W, colbase, qb0, qb1, qb2, qb3, qbn, a1);
        }

        const int buf = t & 1;
        if (gl) {
            part0[buf][wv][wl] = a0;
            part1[buf][wv][wl] = a1;
            partF[buf][wv][wl] = aF;
        }
        fmask = __ballot(ivn > 0.5f);   // FF mask for step t+1 (per-wave reg)
        __syncthreads();                // partials of ALL waves visible

        // ---- tail (threads 0..191): reduce, LIF, publish FIRST, store ----
        if (tid < 192) {
            const float* p0 = (const float*)&part0[buf][0][0];
            const float* p1 = (const float*)&part1[buf][0][0];
            const float* pF = (const float*)&partF[buf][0][0];
            float z0s = 0.f, z1s = 0.f, zFs = 0.f;
            #pragma unroll
            for (int k = 0; k < 12; ++k) {
                z0s += p0[k * 192 + tid];
                z1s += p1[k * 192 + tid];
                zFs += pF[k * 192 + tid];
            }
            z0s *= s0m; z1s *= s1m; zFs *= sFm;
            x0 = ar0 * x0 + z0s;  g0 = ad0 * g0 + x0;   // syn0 (pre ct0)
            x1 = ar1 * x1 + z0s;  g1 = ad1 * g1 + x1;   // syn1 (pre ct0, same z0)
            x2 = ar2 * x2 + z1s;  g2 = ad2 * g2 + x2;   // syn2 (pre ct1)
            xF = arF * xF + zFs;  gF = adF * gF + xF;   // feed-forward
            const float gtot = g0 + 0.5f * g1 + g2 + gF;   // gbar=[1,.5,1], FF 1
            const float gE   = -70.0f * g2;                // gbar*Erev=[0,0,-70], FF 0
            const float Isyn = gE - gtot * U;
            float Un = U + lc * (10.0f * (-65.0f - U) + Isyn);
            if (refc > 0.0f) Un = -65.0f;
            refc = fmaxf(refc - 1.0f, 0.0f);
            const bool s = (Un - (-50.0f)) >= 0.0f;
            // publish ASAP: waves 0..2 cover 64 consecutive neurons each;
            // lanes 0/32 store (tag<<32)|half — flag and data in one word.
            const uint64_t bal = __ballot(s);
            if (wl == 0 || wl == 32) {
                const uint32_t half = (wl == 0) ? (uint32_t)bal : (uint32_t)(bal >> 32);
                const uint32_t word = (uint32_t)(j * 6 + wv * 2) + (wl == 32 ? 1u : 0u);
                const uint32_t widx = (uint32_t)(btbase + t) * 48u + word;
                const uint64_t v = ((uint64_t)(uint32_t)(t + 1) << 32) | half;
                __hip_atomic_store(&recpub[widx], v, __ATOMIC_RELAXED,
                                   __HIP_MEMORY_SCOPE_AGENT);
            }
            const float Uo = s ? -65.0f : Un;
            refc = s ? refsteps : refc;
            U = Uo;
            const uint32_t oidx = (uint32_t)(btbase + t) * 1536u + (uint32_t)m;
            __builtin_nontemporal_store(s ? 1.0f : 0.0f, &out[oidx]);
            __builtin_nontemporal_store(Uo, &out[12582912u + oidx]);
        }
        // no second barrier: partials double-buffered; no wave can reach step
        // t+2's writes before all waves passed step t+1's barrier.
    }
}

extern "C" void kernel_launch(void* const* d_in, const int* in_sizes, int n_in,
                              void* d_out, int out_size, void* d_ws, size_t ws_size,
                              hipStream_t stream) {
    const float* I   = (const float*)d_in[0];   // input_spikes (32,256,768)
    const float* W   = (const float*)d_in[1];   // weights (1536,1536)
    const float* WF  = (const float*)d_in[2];   // weights_FF (768,1536)
    const float* sf  = (const float*)d_in[3];   // scaling_factors (2,2)
    const float* sfF = (const float*)d_in[4];   // scaling_factors_FF (1,2)
    const int*   ct  = (const int*)d_in[5];     // cell_type_indices (1536)
    // d_in[6] cell_type_indices_FF: all zeros, folded into sfF indexing.

    uint64_t* recpub = (uint64_t*)d_ws;   // 32*256*48*8 = 3,145,728 B

    snn_lif_kernel<<<dim3(256), dim3(768), 0, stream>>>(
        I, W, WF, sf, sfF, ct, (float*)d_out, recpub);
}